// Round 27
// baseline (688.056 us; speedup 1.0000x reference)
//
#include <hip/hip_runtime.h>
#include <math.h>

#define NN   65536
#define EE   32768
#define HH   256
#define KK   24
#define DDIM 1280
#define OUTD 512
#define KT   (DDIM / 32)   // 40 K-steps of 32
#define GCAP 1024
#define RSTRIDE 1296       // 1280 + 16 halves pad

typedef _Float16 half8 __attribute__((ext_vector_type(8)));
typedef _Float16 half4 __attribute__((ext_vector_type(4)));
typedef float    f32x4 __attribute__((ext_vector_type(4)));

__device__ __forceinline__ float elu1(float x) { return x > 0.f ? x : expm1f(x); }

__device__ __forceinline__ void gl16(const void* g, void* l) {
    __builtin_amdgcn_global_load_lds(
        (const __attribute__((address_space(1))) void*)g,
        (__attribute__((address_space(3))) void*)l, 16, 0, 0);
}

// ---------------------------------------------------------------------------
// Fragment-major layout: element (row, k) ->
// idx = ((row>>7)*KT + (k>>5))*4096 + ((row>>4)&7)*512
//       + ((row&15) + 16*((k&31)>>3))*8 + (k&7)   [halves]
// ---------------------------------------------------------------------------
__global__ __launch_bounds__(256) void prep_kernel(
    const float* __restrict__ Wd, const float* __restrict__ Wo,
    const float* __restrict__ X,
    _Float16* __restrict__ W16d, _Float16* __restrict__ W16o,
    _Float16* __restrict__ X16, int* __restrict__ cnt,
    int* __restrict__ sperm)
{
    const int b = blockIdx.x;
    const int lane = threadIdx.x & 63;
    if (b < 2400) {                      // 3 square layers: 800 blocks each
        const int l = b / 800;
        const int s = (b % 800) * 4 + (threadIdx.x >> 6);
        const int nt = s & 7, nb = (s >> 3) % 10, kt = s / 80;
        const int kbase = kt * 32 + 8 * (lane >> 4);
        const int n     = nb * 128 + nt * 16 + (lane & 15);
        const float* W = Wd + (size_t)l * DDIM * DDIM;
        half8 v;
        #pragma unroll
        for (int j = 0; j < 8; ++j) v[j] = (_Float16)W[(size_t)(kbase + j) * DDIM + n];
        ((half8*)(W16d + (size_t)l * DDIM * DDIM))[(size_t)s * 64 + lane] = v;
    } else if (b < 2720) {               // output layer: 320 blocks
        const int s = (b - 2400) * 4 + (threadIdx.x >> 6);
        const int nt = s & 7, nb = (s >> 3) % 4, kt = s / 32;
        const int kbase = kt * 32 + 8 * (lane >> 4);
        const int n     = nb * 128 + nt * 16 + (lane & 15);
        half8 v;
        #pragma unroll
        for (int j = 0; j < 8; ++j) v[j] = (_Float16)Wo[(size_t)(kbase + j) * OUTD + n];
        ((half8*)W16o)[(size_t)s * 64 + lane] = v;
    } else if (b == 2720) {
        if (threadIdx.x < 64) cnt[threadIdx.x] = 0;
    } else if (b < 6817) {               // X conversion: 4096 blocks, 16 rows each
        const int a = b - 2721;
        const int r  = a * 16 + (threadIdx.x >> 4);
        const int c0 = (threadIdx.x & 15) * 16;
        const float4* s4 = (const float4*)(X + (size_t)r * HH + c0);
        const float4 f0 = s4[0], f1 = s4[1], f2 = s4[2], f3 = s4[3];
        half8 o0, o1;
        o0[0]=(_Float16)f0.x; o0[1]=(_Float16)f0.y; o0[2]=(_Float16)f0.z; o0[3]=(_Float16)f0.w;
        o0[4]=(_Float16)f1.x; o0[5]=(_Float16)f1.y; o0[6]=(_Float16)f1.z; o0[7]=(_Float16)f1.w;
        o1[0]=(_Float16)f2.x; o1[1]=(_Float16)f2.y; o1[2]=(_Float16)f2.z; o1[3]=(_Float16)f2.w;
        o1[4]=(_Float16)f3.x; o1[5]=(_Float16)f3.y; o1[6]=(_Float16)f3.z; o1[7]=(_Float16)f3.w;
        *(half8*)(X16 + (size_t)r * HH + c0)     = o0;
        *(half8*)(X16 + (size_t)r * HH + c0 + 8) = o1;
    } else {                             // sperm identity: 32 blocks x 1024 ints
        const int i0 = (b - 6817) * 1024 + threadIdx.x * 4;
        if (i0 < EE)
            *(int4*)(sperm + i0) = make_int4(i0, i0 + 1, i0 + 2, i0 + 3);
    }
}

// bucket edges by graph, LDS-aggregated (order-independent output)
__global__ __launch_bounds__(256) void scatter_kernel(
    const int* __restrict__ src_idx, const int* __restrict__ batch_vec,
    int* __restrict__ perm, int* __restrict__ cnt, int nE)
{
    __shared__ int lc[64];
    __shared__ int lbase[64];
    const int tid = threadIdx.x;
    if (tid < 64) lc[tid] = 0;
    __syncthreads();
    const int e = blockIdx.x * 256 + tid;
    int g = -1, li = 0;
    if (e < nE) {
        g = batch_vec[src_idx[e]];
        li = atomicAdd(&lc[g], 1);
    }
    __syncthreads();
    if (tid < 64 && lc[tid] > 0) lbase[tid] = atomicAdd(&cnt[tid], lc[tid]);
    __syncthreads();
    if (e >= nE) return;
    const int idx = lbase[g] + li;
    if (idx < GCAP) perm[g * GCAP + idx] = e;
}

// compact GCAP-strided perm into dense slot order (sperm[slot] = edge),
// with the 64-entry exclusive prefix computed inline per block (cheap).
__global__ __launch_bounds__(256) void compact_kernel(
    const int* __restrict__ perm, const int* __restrict__ cnt,
    int* __restrict__ sperm)
{
    __shared__ int pre[64];
    if (threadIdx.x == 0) {
        int acc = 0;
        #pragma unroll
        for (int g = 0; g < 64; ++g) { pre[g] = acc; acc += min(cnt[g], GCAP); }
    }
    __syncthreads();
    const int id = blockIdx.x * 256 + threadIdx.x;   // 64*GCAP ids
    const int g = id >> 10, idx = id & (GCAP - 1);
    if (idx < min(cnt[g], GCAP))
        sperm[pre[g] + idx] = perm[id];
}

// ---------------------------------------------------------------------------
// Feature assembly (R24-validated): block = 16 consecutive slots; bucketed
// reads + coalesced fragment-major writes via LDS transpose.
// ---------------------------------------------------------------------------
__global__ __launch_bounds__(256) void feats16t_kernel(
    const _Float16* __restrict__ X16, const int* __restrict__ sperm,
    const int* __restrict__ src_idx, const int* __restrict__ dst_idx,
    const int* __restrict__ batch_vec, const int* __restrict__ ptrv,
    const int* __restrict__ sl, const int* __restrict__ sr,
    const float* __restrict__ elem, const float* __restrict__ emb,
    const float* __restrict__ stat,
    _Float16* __restrict__ F16)
{
    __shared__ _Float16 rows[16][RSTRIDE];

    const int p  = blockIdx.x;
    int lb = p;
    if ((gridDim.x & 7) == 0) {
        const int chunkb = gridDim.x >> 3;
        lb = (p & 7) * chunkb + (p >> 3);
    }
    const int wv   = threadIdx.x >> 6;
    const int lane = threadIdx.x & 63;
    const int s0   = lb * 16;

    const half4* Xh = (const half4*)X16;

    #pragma unroll
    for (int it = 0; it < 4; ++it) {
        const int r = wv * 4 + it;
        const int e = sperm[s0 + r];
        const int src = src_idx[e];
        const int dst = dst_idx[e];
        const int off = ptrv[batch_vec[src]];
        _Float16* row = &rows[r][0];

        *(half4*)(row + 0 * 256 + lane * 4) = Xh[(size_t)src * 64 + lane];
        *(half4*)(row + 1 * 256 + lane * 4) = Xh[(size_t)dst * 64 + lane];

        float4 sL = make_float4(0.f, 0.f, 0.f, 0.f);
        float4 sR = make_float4(0.f, 0.f, 0.f, 0.f);
        int cL = 0, cR = 0;
        #pragma unroll
        for (int k = 0; k < KK; ++k) {
            const int il  = sl[e * KK + k] + off;
            const int ir  = sr[e * KK + k] + off;
            const int okL = il >= 0;
            const int okR = ir >= 0;
            const float wL = okL ? 1.f : 0.f;
            const float wR = okR ? 1.f : 0.f;
            const half4 vl = Xh[(size_t)(okL ? il : 0) * 64 + lane];
            const half4 vr = Xh[(size_t)(okR ? ir : 0) * 64 + lane];
            sL.x += (float)vl[0] * wL; sL.y += (float)vl[1] * wL;
            sL.z += (float)vl[2] * wL; sL.w += (float)vl[3] * wL;
            sR.x += (float)vr[0] * wR; sR.y += (float)vr[1] * wR;
            sR.z += (float)vr[2] * wR; sR.w += (float)vr[3] * wR;
            cL += okL; cR += okR;
        }
        const float rL = cL > 0 ? 1.f / (float)cL : 0.f;
        const float rR = cR > 0 ? 1.f / (float)cR : 0.f;
        half4 h2, h3;
        h2[0]=(_Float16)(sL.x*rL); h2[1]=(_Float16)(sL.y*rL);
        h2[2]=(_Float16)(sL.z*rL); h2[3]=(_Float16)(sL.w*rL);
        h3[0]=(_Float16)(sR.x*rR); h3[1]=(_Float16)(sR.y*rR);
        h3[2]=(_Float16)(sR.z*rR); h3[3]=(_Float16)(sR.w*rR);
        *(half4*)(row + 2 * 256 + lane * 4) = h2;
        *(half4*)(row + 3 * 256 + lane * 4) = h3;

        float4 tail;
        if (lane < 6)       tail = ((const float4*)(elem + (size_t)e * 24))[lane];
        else if (lane < 56) tail = ((const float4*)(emb  + (size_t)e * 200))[lane - 6];
        else                tail = ((const float4*)(stat + (size_t)e * 32))[lane - 56];
        half4 h4;
        h4[0]=(_Float16)tail.x; h4[1]=(_Float16)tail.y;
        h4[2]=(_Float16)tail.z; h4[3]=(_Float16)tail.w;
        *(half4*)(row + 4 * 256 + lane * 4) = h4;
    }

    __syncthreads();

    const int t = threadIdx.x;
    const size_t mt  = (size_t)(s0 >> 7) * KT;
    const int    sr8 = (s0 >> 4) & 7;
    #pragma unroll
    for (int i = 0; i < 10; ++i) {
        const int gc = i * 256 + t;
        const int kt = gc >> 6;
        const int c  = gc & 63;
        const uint4 v = *(const uint4*)&rows[c & 15][kt * 32 + (c >> 4) * 8];
        *(uint4*)(F16 + ((mt + kt) * 4096 + (size_t)sr8 * 512 + (size_t)c * 8)) = v;
    }
}

// ---------------------------------------------------------------------------
// MFMA GEMM (gemm10): same 3-buffer counted-vmcnt pipeline as the validated
// gemm7, but WITHOUT the read->MFMA order pinning: ds_reads and MFMAs sit in
// one compiler-scheduled region (fine-grained lgkmcnt interleave, m97-style),
// so LDS latency hides under MFMA issue. The lgkm(0) before barrier-2 is
// ~free (MFMAs already forced read retirement) and covers resv captures.
// STAGE after barrier-2 as before. Residual from LDS A-tiles; H16 staged
// through LDS; OUT32 un-permutes rows via operm.
// ---------------------------------------------------------------------------
template<bool RESID, bool OUT32, bool H16>
__global__ __launch_bounds__(256) void mfma_gemm10(
    const _Float16* __restrict__ A16,
    const _Float16* __restrict__ W16, const float* __restrict__ bias,
    float* __restrict__ C32, _Float16* __restrict__ C16,
    const int* __restrict__ operm,
    int N, int nbN)
{
    __shared__ __align__(16) char sA[3][8192];
    __shared__ __align__(16) char sB[3][8192];

    const int t    = threadIdx.x;
    const int wid  = t >> 6;
    const int lane = t & 63;

    int m_t, n_t;
    if ((gridDim.y & 7) == 0) {
        const int flat = blockIdx.y * gridDim.x + blockIdx.x;
        m_t = (flat & 7) + 8 * (flat / (8 * gridDim.x));
        n_t = (flat >> 3) % gridDim.x;
    } else {
        m_t = blockIdx.y; n_t = blockIdx.x;
    }

    f32x4 acc[2][8];
    #pragma unroll
    for (int i = 0; i < 2; ++i)
        #pragma unroll
        for (int j = 0; j < 8; ++j) acc[i][j] = (f32x4){0.f, 0.f, 0.f, 0.f};

    _Float16 resv[4][2][2][4];

    const char* Abase = (const char*)A16 + (size_t)m_t * KT * 8192;
    const char* Bbase = (const char*)W16;

#define STAGE(d, ktv)                                                           \
    {                                                                           \
        const char* Ak = Abase + (size_t)(ktv) * 8192 + wid * 1024 + lane * 16; \
        const char* Bk = Bbase + ((size_t)(ktv) * nbN + n_t) * 8192             \
                         + wid * 1024 + lane * 16;                              \
        gl16(Ak,        sA[d] + wid * 1024);                                    \
        gl16(Ak + 4096, sA[d] + (4 + wid) * 1024);                              \
        gl16(Bk,        sB[d] + wid * 1024);                                    \
        gl16(Bk + 4096, sB[d] + (4 + wid) * 1024);                              \
    }

    STAGE(0, 0);
    STAGE(1, 1);
    STAGE(2, 2);

    int cur = 0;
    for (int kt = 0; kt < KT; ++kt) {
        if (kt + 2 < KT)      asm volatile("s_waitcnt vmcnt(8)" ::: "memory");
        else if (kt + 1 < KT) asm volatile("s_waitcnt vmcnt(4)" ::: "memory");
        else                  asm volatile("s_waitcnt vmcnt(0)" ::: "memory");
        __builtin_amdgcn_sched_barrier(0);
        __builtin_amdgcn_s_barrier();          // stage kt visible to all waves
        __builtin_amdgcn_sched_barrier(0);

        // reads + MFMAs in ONE compiler-scheduled region: hipcc interleaves
        // fine-grained lgkmcnt waits so LDS latency hides under MFMA issue.
        const half8* pa = (const half8*)sA[cur];
        const half8* pb = (const half8*)sB[cur];
        const half8 af0 = pa[(2 * wid)     * 64 + lane];
        const half8 af1 = pa[(2 * wid + 1) * 64 + lane];
        half8 bf[8];
        #pragma unroll
        for (int j = 0; j < 8; ++j) bf[j] = pb[j * 64 + lane];

        if (RESID) {
            #pragma unroll
            for (int q = 0; q < 4; ++q) {
                if (kt == n_t * 4 + q) {
                    #pragma unroll
                    for (int i = 0; i < 2; ++i)
                        #pragma unroll
                        for (int jj = 0; jj < 2; ++jj)
                            #pragma unroll
                            for (int r = 0; r < 4; ++r) {
                                const int chunk = ((lane >> 4) * 4 + r)
                                                + 16 * (jj * 2 + ((lane >> 3) & 1));
                                resv[q][i][jj][r] = *(const _Float16*)
                                    (sA[cur] + (wid * 2 + i) * 1024
                                             + chunk * 16 + (lane & 7) * 2);
                            }
                }
            }
        }

        __builtin_amdgcn_s_setprio(1);
        #pragma unroll
        for (int j = 0; j < 8; ++j) {
            acc[0][j] = __builtin_amdgcn_mfma_f32_16x16x32_f16(af0, bf[j], acc[0][j], 0, 0, 0);
            acc[1][j] = __builtin_amdgcn_mfma_f32_16x16x32_f16(af1, bf[j], acc[1][j], 0, 0, 0);
        }
        __builtin_amdgcn_s_setprio(0);

        // nearly-free: MFMAs already retired the frag reads; covers resv.
        asm volatile("s_waitcnt lgkmcnt(0)" ::: "memory");
        __builtin_amdgcn_sched_barrier(0);
        __builtin_amdgcn_s_barrier();          // all waves done with buf[cur]
        __builtin_amdgcn_sched_barrier(0);

        if (kt + 3 < KT) STAGE(cur, kt + 3);
        __builtin_amdgcn_sched_barrier(0);

        cur = (cur == 2) ? 0 : cur + 1;
    }
#undef STAGE

    if (H16) {
        char* Cb = (char*)C16 + ((size_t)m_t * 40 + n_t * 4) * 8192;
        #pragma unroll
        for (int q = 0; q < 4; ++q) {
            #pragma unroll
            for (int i = 0; i < 2; ++i)
                #pragma unroll
                for (int jj = 0; jj < 2; ++jj) {
                    const int j = 2 * q + jj;
                    const int col = n_t * 128 + j * 16 + (lane & 15);
                    const float bv = bias[col];
                    #pragma unroll
                    for (int r = 0; r < 4; ++r) {
                        float v = acc[i][j][r] + bv;
                        v = elu1(v) + (float)resv[q][i][jj][r];
                        const int chunk = ((lane >> 4) * 4 + r)
                                        + 16 * (jj * 2 + ((lane >> 3) & 1));
                        *(_Float16*)(sA[0] + (wid * 2 + i) * 1024
                                           + chunk * 16 + (lane & 7) * 2)
                            = (_Float16)v;
                    }
                }
            __syncthreads();
            *(uint4*)(Cb + (size_t)q * 8192 + t * 32) =
                *(const uint4*)(sA[0] + t * 32);
            *(uint4*)(Cb + (size_t)q * 8192 + t * 32 + 16) =
                *(const uint4*)(sA[0] + t * 32 + 16);
            if (q < 3) __syncthreads();
        }
    } else {
        const int m0 = m_t * 128;
        #pragma unroll
        for (int i = 0; i < 2; ++i) {
            #pragma unroll
            for (int j = 0; j < 8; ++j) {
                const int col = n_t * 128 + j * 16 + (lane & 15);
                const float bv = bias[col];
                #pragma unroll
                for (int r = 0; r < 4; ++r) {
                    const int row = m0 + wid * 32 + i * 16 + (lane >> 4) * 4 + r;
                    float v = acc[i][j][r] + bv;
                    if (OUT32) {
                        const int erow = operm[row];   // slot -> edge
                        C32[(size_t)erow * N + col] = v;
                    }
                }
            }
        }
    }
}

extern "C" void kernel_launch(void* const* d_in, const int* in_sizes, int n_in,
                              void* d_out, int out_size, void* d_ws, size_t ws_size,
                              hipStream_t stream) {
    const float* X          = (const float*)d_in[0];
    const int*   edge_index = (const int*)d_in[1];
    const int*   batch_vec  = (const int*)d_in[2];
    const int*   ptrv       = (const int*)d_in[3];
    const int*   sl         = (const int*)d_in[4];
    const int*   sr         = (const int*)d_in[5];
    const float* elem       = (const float*)d_in[6];
    const float* emb        = (const float*)d_in[7];
    const float* stat       = (const float*)d_in[8];
    const float* Wd         = (const float*)d_in[9];
    const float* bd         = (const float*)d_in[10];
    const float* Wo         = (const float*)d_in[11];
    const float* bo         = (const float*)d_in[12];
    float* out = (float*)d_out;

    // ws: [W16d x3 | W16o | X16 | perm | cnt | sperm | h16 a,b]
    _Float16* W16d = (_Float16*)d_ws;
    _Float16* W16o = W16d + (size_t)3 * DDIM * DDIM;
    _Float16* X16  = W16o + (size_t)DDIM * OUTD;
    int* perm    = (int*)(X16 + (size_t)NN * HH);
    int* cnt     = perm + (size_t)64 * GCAP;
    int* sperm   = cnt + 64;
    char* hbase  = (char*)(sperm + EE);
    hbase = (char*)(((size_t)hbase + 255) & ~(size_t)255);
    const size_t rem = ws_size - (size_t)(hbase - (char*)d_ws);

    // Single chunk: working set ~211 MB -> L3-resident; minimal dispatches.
    int CH = EE;
    while (CH > 2048 && (size_t)CH * DDIM * 4 > rem) CH >>= 1;   // 4 B/elem
    _Float16* f16a = (_Float16*)hbase;
    _Float16* f16b = f16a + (size_t)CH * DDIM;

    prep_kernel<<<6849, 256, 0, stream>>>(Wd, Wo, X, W16d, W16o, X16, cnt, sperm);

    for (int e0 = 0; e0 < EE; e0 += CH) {
        scatter_kernel<<<CH / 256, 256, 0, stream>>>(
            edge_index + e0, batch_vec, perm, cnt, CH);
        compact_kernel<<<64 * GCAP / 256, 256, 0, stream>>>(perm, cnt, sperm);

        feats16t_kernel<<<CH / 16, 256, 0, stream>>>(
            X16, sperm, edge_index + e0, edge_index + EE + e0,
            batch_vec, ptrv,
            sl + (size_t)e0 * KK, sr + (size_t)e0 * KK,
            elem + (size_t)e0 * 24, emb + (size_t)e0 * 200,
            stat + (size_t)e0 * 32, f16a);

        dim3 gd(10, CH / 128);
        mfma_gemm10<true, false, true><<<gd, 256, 0, stream>>>(
            f16a, W16d + 0 * (size_t)DDIM * DDIM, bd + 0 * DDIM,
            nullptr, f16b, nullptr, DDIM, 10);
        mfma_gemm10<true, false, true><<<gd, 256, 0, stream>>>(
            f16b, W16d + 1 * (size_t)DDIM * DDIM, bd + 1 * DDIM,
            nullptr, f16a, nullptr, DDIM, 10);
        mfma_gemm10<true, false, true><<<gd, 256, 0, stream>>>(
            f16a, W16d + 2 * (size_t)DDIM * DDIM, bd + 2 * DDIM,
            nullptr, f16b, nullptr, DDIM, 10);

        dim3 go(4, CH / 128);
        mfma_gemm10<false, true, false><<<go, 256, 0, stream>>>(
            f16b, W16o, bo, out + (size_t)e0 * OUTD, nullptr, sperm, OUTD, 4);
    }
}

// Round 28
// 655.695 us; speedup vs baseline: 1.0494x; 1.0494x over previous
//
#include <hip/hip_runtime.h>
#include <math.h>

#define NN   65536
#define EE   32768
#define HH   256
#define KK   24
#define DDIM 1280
#define OUTD 512
#define KT   (DDIM / 32)   // 40 K-steps of 32
#define GCAP 1024
#define RSTRIDE 1296       // 1280 + 16 halves pad

typedef _Float16 half8 __attribute__((ext_vector_type(8)));
typedef _Float16 half4 __attribute__((ext_vector_type(4)));
typedef float    f32x4 __attribute__((ext_vector_type(4)));

__device__ __forceinline__ float elu1(float x) { return x > 0.f ? x : expm1f(x); }

__device__ __forceinline__ void gl16(const void* g, void* l) {
    __builtin_amdgcn_global_load_lds(
        (const __attribute__((address_space(1))) void*)g,
        (__attribute__((address_space(3))) void*)l, 16, 0, 0);
}

// ---------------------------------------------------------------------------
// Fragment-major layout: element (row, k) ->
// idx = ((row>>7)*KT + (k>>5))*4096 + ((row>>4)&7)*512
//       + ((row&15) + 16*((k&31)>>3))*8 + (k&7)   [halves]
// ---------------------------------------------------------------------------
__global__ __launch_bounds__(256) void prep_kernel(
    const float* __restrict__ Wd, const float* __restrict__ Wo,
    const float* __restrict__ X,
    _Float16* __restrict__ W16d, _Float16* __restrict__ W16o,
    _Float16* __restrict__ X16, int* __restrict__ cnt,
    int* __restrict__ sperm)
{
    const int b = blockIdx.x;
    const int lane = threadIdx.x & 63;
    if (b < 2400) {                      // 3 square layers: 800 blocks each
        const int l = b / 800;
        const int s = (b % 800) * 4 + (threadIdx.x >> 6);
        const int nt = s & 7, nb = (s >> 3) % 10, kt = s / 80;
        const int kbase = kt * 32 + 8 * (lane >> 4);
        const int n     = nb * 128 + nt * 16 + (lane & 15);
        const float* W = Wd + (size_t)l * DDIM * DDIM;
        half8 v;
        #pragma unroll
        for (int j = 0; j < 8; ++j) v[j] = (_Float16)W[(size_t)(kbase + j) * DDIM + n];
        ((half8*)(W16d + (size_t)l * DDIM * DDIM))[(size_t)s * 64 + lane] = v;
    } else if (b < 2720) {               // output layer: 320 blocks
        const int s = (b - 2400) * 4 + (threadIdx.x >> 6);
        const int nt = s & 7, nb = (s >> 3) % 4, kt = s / 32;
        const int kbase = kt * 32 + 8 * (lane >> 4);
        const int n     = nb * 128 + nt * 16 + (lane & 15);
        half8 v;
        #pragma unroll
        for (int j = 0; j < 8; ++j) v[j] = (_Float16)Wo[(size_t)(kbase + j) * OUTD + n];
        ((half8*)W16o)[(size_t)s * 64 + lane] = v;
    } else if (b == 2720) {
        if (threadIdx.x < 64) cnt[threadIdx.x] = 0;
    } else if (b < 6817) {               // X conversion: 4096 blocks, 16 rows each
        const int a = b - 2721;
        const int r  = a * 16 + (threadIdx.x >> 4);
        const int c0 = (threadIdx.x & 15) * 16;
        const float4* s4 = (const float4*)(X + (size_t)r * HH + c0);
        const float4 f0 = s4[0], f1 = s4[1], f2 = s4[2], f3 = s4[3];
        half8 o0, o1;
        o0[0]=(_Float16)f0.x; o0[1]=(_Float16)f0.y; o0[2]=(_Float16)f0.z; o0[3]=(_Float16)f0.w;
        o0[4]=(_Float16)f1.x; o0[5]=(_Float16)f1.y; o0[6]=(_Float16)f1.z; o0[7]=(_Float16)f1.w;
        o1[0]=(_Float16)f2.x; o1[1]=(_Float16)f2.y; o1[2]=(_Float16)f2.z; o1[3]=(_Float16)f2.w;
        o1[4]=(_Float16)f3.x; o1[5]=(_Float16)f3.y; o1[6]=(_Float16)f3.z; o1[7]=(_Float16)f3.w;
        *(half8*)(X16 + (size_t)r * HH + c0)     = o0;
        *(half8*)(X16 + (size_t)r * HH + c0 + 8) = o1;
    } else {                             // sperm identity: 32 blocks x 1024 ints
        const int i0 = (b - 6817) * 1024 + threadIdx.x * 4;
        if (i0 < EE)
            *(int4*)(sperm + i0) = make_int4(i0, i0 + 1, i0 + 2, i0 + 3);
    }
}

// bucket edges by graph, LDS-aggregated (order-independent output)
__global__ __launch_bounds__(256) void scatter_kernel(
    const int* __restrict__ src_idx, const int* __restrict__ batch_vec,
    int* __restrict__ perm, int* __restrict__ cnt, int nE)
{
    __shared__ int lc[64];
    __shared__ int lbase[64];
    const int tid = threadIdx.x;
    if (tid < 64) lc[tid] = 0;
    __syncthreads();
    const int e = blockIdx.x * 256 + tid;
    int g = -1, li = 0;
    if (e < nE) {
        g = batch_vec[src_idx[e]];
        li = atomicAdd(&lc[g], 1);
    }
    __syncthreads();
    if (tid < 64 && lc[tid] > 0) lbase[tid] = atomicAdd(&cnt[tid], lc[tid]);
    __syncthreads();
    if (e >= nE) return;
    const int idx = lbase[g] + li;
    if (idx < GCAP) perm[g * GCAP + idx] = e;
}

// compact GCAP-strided perm into dense slot order (sperm[slot] = edge),
// with the 64-entry exclusive prefix computed inline per block (cheap).
__global__ __launch_bounds__(256) void compact_kernel(
    const int* __restrict__ perm, const int* __restrict__ cnt,
    int* __restrict__ sperm)
{
    __shared__ int pre[64];
    if (threadIdx.x == 0) {
        int acc = 0;
        #pragma unroll
        for (int g = 0; g < 64; ++g) { pre[g] = acc; acc += min(cnt[g], GCAP); }
    }
    __syncthreads();
    const int id = blockIdx.x * 256 + threadIdx.x;   // 64*GCAP ids
    const int g = id >> 10, idx = id & (GCAP - 1);
    if (idx < min(cnt[g], GCAP))
        sperm[pre[g] + idx] = perm[id];
}

// ---------------------------------------------------------------------------
// Feature assembly (R24-validated): block = 16 consecutive slots; bucketed
// reads + coalesced fragment-major writes via LDS transpose.
// ---------------------------------------------------------------------------
__global__ __launch_bounds__(256) void feats16t_kernel(
    const _Float16* __restrict__ X16, const int* __restrict__ sperm,
    const int* __restrict__ src_idx, const int* __restrict__ dst_idx,
    const int* __restrict__ batch_vec, const int* __restrict__ ptrv,
    const int* __restrict__ sl, const int* __restrict__ sr,
    const float* __restrict__ elem, const float* __restrict__ emb,
    const float* __restrict__ stat,
    _Float16* __restrict__ F16)
{
    __shared__ _Float16 rows[16][RSTRIDE];

    const int p  = blockIdx.x;
    int lb = p;
    if ((gridDim.x & 7) == 0) {
        const int chunkb = gridDim.x >> 3;
        lb = (p & 7) * chunkb + (p >> 3);
    }
    const int wv   = threadIdx.x >> 6;
    const int lane = threadIdx.x & 63;
    const int s0   = lb * 16;

    const half4* Xh = (const half4*)X16;

    #pragma unroll
    for (int it = 0; it < 4; ++it) {
        const int r = wv * 4 + it;
        const int e = sperm[s0 + r];
        const int src = src_idx[e];
        const int dst = dst_idx[e];
        const int off = ptrv[batch_vec[src]];
        _Float16* row = &rows[r][0];

        *(half4*)(row + 0 * 256 + lane * 4) = Xh[(size_t)src * 64 + lane];
        *(half4*)(row + 1 * 256 + lane * 4) = Xh[(size_t)dst * 64 + lane];

        float4 sL = make_float4(0.f, 0.f, 0.f, 0.f);
        float4 sR = make_float4(0.f, 0.f, 0.f, 0.f);
        int cL = 0, cR = 0;
        #pragma unroll
        for (int k = 0; k < KK; ++k) {
            const int il  = sl[e * KK + k] + off;
            const int ir  = sr[e * KK + k] + off;
            const int okL = il >= 0;
            const int okR = ir >= 0;
            const float wL = okL ? 1.f : 0.f;
            const float wR = okR ? 1.f : 0.f;
            const half4 vl = Xh[(size_t)(okL ? il : 0) * 64 + lane];
            const half4 vr = Xh[(size_t)(okR ? ir : 0) * 64 + lane];
            sL.x += (float)vl[0] * wL; sL.y += (float)vl[1] * wL;
            sL.z += (float)vl[2] * wL; sL.w += (float)vl[3] * wL;
            sR.x += (float)vr[0] * wR; sR.y += (float)vr[1] * wR;
            sR.z += (float)vr[2] * wR; sR.w += (float)vr[3] * wR;
            cL += okL; cR += okR;
        }
        const float rL = cL > 0 ? 1.f / (float)cL : 0.f;
        const float rR = cR > 0 ? 1.f / (float)cR : 0.f;
        half4 h2, h3;
        h2[0]=(_Float16)(sL.x*rL); h2[1]=(_Float16)(sL.y*rL);
        h2[2]=(_Float16)(sL.z*rL); h2[3]=(_Float16)(sL.w*rL);
        h3[0]=(_Float16)(sR.x*rR); h3[1]=(_Float16)(sR.y*rR);
        h3[2]=(_Float16)(sR.z*rR); h3[3]=(_Float16)(sR.w*rR);
        *(half4*)(row + 2 * 256 + lane * 4) = h2;
        *(half4*)(row + 3 * 256 + lane * 4) = h3;

        float4 tail;
        if (lane < 6)       tail = ((const float4*)(elem + (size_t)e * 24))[lane];
        else if (lane < 56) tail = ((const float4*)(emb  + (size_t)e * 200))[lane - 6];
        else                tail = ((const float4*)(stat + (size_t)e * 32))[lane - 56];
        half4 h4;
        h4[0]=(_Float16)tail.x; h4[1]=(_Float16)tail.y;
        h4[2]=(_Float16)tail.z; h4[3]=(_Float16)tail.w;
        *(half4*)(row + 4 * 256 + lane * 4) = h4;
    }

    __syncthreads();

    const int t = threadIdx.x;
    const size_t mt  = (size_t)(s0 >> 7) * KT;
    const int    sr8 = (s0 >> 4) & 7;
    #pragma unroll
    for (int i = 0; i < 10; ++i) {
        const int gc = i * 256 + t;
        const int kt = gc >> 6;
        const int c  = gc & 63;
        const uint4 v = *(const uint4*)&rows[c & 15][kt * 32 + (c >> 4) * 8];
        *(uint4*)(F16 + ((mt + kt) * 4096 + (size_t)sr8 * 512 + (size_t)c * 8)) = v;
    }
}

// ---------------------------------------------------------------------------
// MFMA GEMM, counted-vmcnt triple-buffer (R24/R26-validated gemm7).
// Residual captured from LDS A-tiles; H16 staged through LDS for coalesced
// stores. OUT32 un-permutes rows via operm.
// ---------------------------------------------------------------------------
template<bool RESID, bool OUT32, bool H16>
__global__ __launch_bounds__(256) void mfma_gemm7(
    const _Float16* __restrict__ A16,
    const _Float16* __restrict__ W16, const float* __restrict__ bias,
    float* __restrict__ C32, _Float16* __restrict__ C16,
    const int* __restrict__ operm,
    int N, int nbN)
{
    __shared__ __align__(16) char sA[3][8192];
    __shared__ __align__(16) char sB[3][8192];

    const int t    = threadIdx.x;
    const int wid  = t >> 6;
    const int lane = t & 63;

    int m_t, n_t;
    if ((gridDim.y & 7) == 0) {
        const int flat = blockIdx.y * gridDim.x + blockIdx.x;
        m_t = (flat & 7) + 8 * (flat / (8 * gridDim.x));
        n_t = (flat >> 3) % gridDim.x;
    } else {
        m_t = blockIdx.y; n_t = blockIdx.x;
    }

    f32x4 acc[2][8];
    #pragma unroll
    for (int i = 0; i < 2; ++i)
        #pragma unroll
        for (int j = 0; j < 8; ++j) acc[i][j] = (f32x4){0.f, 0.f, 0.f, 0.f};

    _Float16 resv[4][2][2][4];

    const char* Abase = (const char*)A16 + (size_t)m_t * KT * 8192;
    const char* Bbase = (const char*)W16;

#define STAGE(d, ktv)                                                           \
    {                                                                           \
        const char* Ak = Abase + (size_t)(ktv) * 8192 + wid * 1024 + lane * 16; \
        const char* Bk = Bbase + ((size_t)(ktv) * nbN + n_t) * 8192             \
                         + wid * 1024 + lane * 16;                              \
        gl16(Ak,        sA[d] + wid * 1024);                                    \
        gl16(Ak + 4096, sA[d] + (4 + wid) * 1024);                              \
        gl16(Bk,        sB[d] + wid * 1024);                                    \
        gl16(Bk + 4096, sB[d] + (4 + wid) * 1024);                              \
    }

    STAGE(0, 0);
    STAGE(1, 1);
    STAGE(2, 2);

    int cur = 0;
    for (int kt = 0; kt < KT; ++kt) {
        if (kt + 2 < KT)      asm volatile("s_waitcnt vmcnt(8)" ::: "memory");
        else if (kt + 1 < KT) asm volatile("s_waitcnt vmcnt(4)" ::: "memory");
        else                  asm volatile("s_waitcnt vmcnt(0)" ::: "memory");
        __builtin_amdgcn_sched_barrier(0);
        __builtin_amdgcn_s_barrier();
        __builtin_amdgcn_sched_barrier(0);

        const half8* pa = (const half8*)sA[cur];
        const half8* pb = (const half8*)sB[cur];
        const half8 af0 = pa[(2 * wid)     * 64 + lane];
        const half8 af1 = pa[(2 * wid + 1) * 64 + lane];
        half8 bf[8];
        #pragma unroll
        for (int j = 0; j < 8; ++j) bf[j] = pb[j * 64 + lane];

        if (RESID) {
            #pragma unroll
            for (int q = 0; q < 4; ++q) {
                if (kt == n_t * 4 + q) {
                    #pragma unroll
                    for (int i = 0; i < 2; ++i)
                        #pragma unroll
                        for (int jj = 0; jj < 2; ++jj)
                            #pragma unroll
                            for (int r = 0; r < 4; ++r) {
                                const int chunk = ((lane >> 4) * 4 + r)
                                                + 16 * (jj * 2 + ((lane >> 3) & 1));
                                resv[q][i][jj][r] = *(const _Float16*)
                                    (sA[cur] + (wid * 2 + i) * 1024
                                             + chunk * 16 + (lane & 7) * 2);
                            }
                }
            }
        }

        asm volatile("s_waitcnt lgkmcnt(0)" ::: "memory");
        __builtin_amdgcn_sched_barrier(0);
        __builtin_amdgcn_s_barrier();
        __builtin_amdgcn_sched_barrier(0);

        if (kt + 3 < KT) STAGE(cur, kt + 3);
        __builtin_amdgcn_sched_barrier(0);

        __builtin_amdgcn_s_setprio(1);
        #pragma unroll
        for (int j = 0; j < 8; ++j) {
            acc[0][j] = __builtin_amdgcn_mfma_f32_16x16x32_f16(af0, bf[j], acc[0][j], 0, 0, 0);
            acc[1][j] = __builtin_amdgcn_mfma_f32_16x16x32_f16(af1, bf[j], acc[1][j], 0, 0, 0);
        }
        __builtin_amdgcn_s_setprio(0);

        cur = (cur == 2) ? 0 : cur + 1;
    }
#undef STAGE

    if (H16) {
        char* Cb = (char*)C16 + ((size_t)m_t * 40 + n_t * 4) * 8192;
        #pragma unroll
        for (int q = 0; q < 4; ++q) {
            #pragma unroll
            for (int i = 0; i < 2; ++i)
                #pragma unroll
                for (int jj = 0; jj < 2; ++jj) {
                    const int j = 2 * q + jj;
                    const int col = n_t * 128 + j * 16 + (lane & 15);
                    const float bv = bias[col];
                    #pragma unroll
                    for (int r = 0; r < 4; ++r) {
                        float v = acc[i][j][r] + bv;
                        v = elu1(v) + (float)resv[q][i][jj][r];
                        const int chunk = ((lane >> 4) * 4 + r)
                                        + 16 * (jj * 2 + ((lane >> 3) & 1));
                        *(_Float16*)(sA[0] + (wid * 2 + i) * 1024
                                           + chunk * 16 + (lane & 7) * 2)
                            = (_Float16)v;
                    }
                }
            __syncthreads();
            *(uint4*)(Cb + (size_t)q * 8192 + t * 32) =
                *(const uint4*)(sA[0] + t * 32);
            *(uint4*)(Cb + (size_t)q * 8192 + t * 32 + 16) =
                *(const uint4*)(sA[0] + t * 32 + 16);
            if (q < 3) __syncthreads();
        }
    } else {
        const int m0 = m_t * 128;
        #pragma unroll
        for (int i = 0; i < 2; ++i) {
            #pragma unroll
            for (int j = 0; j < 8; ++j) {
                const int col = n_t * 128 + j * 16 + (lane & 15);
                const float bv = bias[col];
                #pragma unroll
                for (int r = 0; r < 4; ++r) {
                    const int row = m0 + wid * 32 + i * 16 + (lane >> 4) * 4 + r;
                    float v = acc[i][j][r] + bv;
                    if (OUT32) {
                        const int erow = operm[row];   // slot -> edge
                        C32[(size_t)erow * N + col] = v;
                    }
                }
            }
        }
    }
}

extern "C" void kernel_launch(void* const* d_in, const int* in_sizes, int n_in,
                              void* d_out, int out_size, void* d_ws, size_t ws_size,
                              hipStream_t stream) {
    const float* X          = (const float*)d_in[0];
    const int*   edge_index = (const int*)d_in[1];
    const int*   batch_vec  = (const int*)d_in[2];
    const int*   ptrv       = (const int*)d_in[3];
    const int*   sl         = (const int*)d_in[4];
    const int*   sr         = (const int*)d_in[5];
    const float* elem       = (const float*)d_in[6];
    const float* emb        = (const float*)d_in[7];
    const float* stat       = (const float*)d_in[8];
    const float* Wd         = (const float*)d_in[9];
    const float* bd         = (const float*)d_in[10];
    const float* Wo         = (const float*)d_in[11];
    const float* bo         = (const float*)d_in[12];
    float* out = (float*)d_out;

    // ws: [W16d x3 | W16o | X16 | perm | cnt | sperm | h16 a,b]
    _Float16* W16d = (_Float16*)d_ws;
    _Float16* W16o = W16d + (size_t)3 * DDIM * DDIM;
    _Float16* X16  = W16o + (size_t)DDIM * OUTD;
    int* perm    = (int*)(X16 + (size_t)NN * HH);
    int* cnt     = perm + (size_t)64 * GCAP;
    int* sperm   = cnt + 64;
    char* hbase  = (char*)(sperm + EE);
    hbase = (char*)(((size_t)hbase + 255) & ~(size_t)255);
    const size_t rem = ws_size - (size_t)(hbase - (char*)d_ws);

    // Single chunk: working set ~211 MB -> L3-resident; minimal dispatches.
    int CH = EE;
    while (CH > 2048 && (size_t)CH * DDIM * 4 > rem) CH >>= 1;   // 4 B/elem
    _Float16* f16a = (_Float16*)hbase;
    _Float16* f16b = f16a + (size_t)CH * DDIM;

    prep_kernel<<<6849, 256, 0, stream>>>(Wd, Wo, X, W16d, W16o, X16, cnt, sperm);

    for (int e0 = 0; e0 < EE; e0 += CH) {
        scatter_kernel<<<CH / 256, 256, 0, stream>>>(
            edge_index + e0, batch_vec, perm, cnt, CH);
        compact_kernel<<<64 * GCAP / 256, 256, 0, stream>>>(perm, cnt, sperm);

        feats16t_kernel<<<CH / 16, 256, 0, stream>>>(
            X16, sperm, edge_index + e0, edge_index + EE + e0,
            batch_vec, ptrv,
            sl + (size_t)e0 * KK, sr + (size_t)e0 * KK,
            elem + (size_t)e0 * 24, emb + (size_t)e0 * 200,
            stat + (size_t)e0 * 32, f16a);

        dim3 gd(10, CH / 128);
        mfma_gemm7<true, false, true><<<gd, 256, 0, stream>>>(
            f16a, W16d + 0 * (size_t)DDIM * DDIM, bd + 0 * DDIM,
            nullptr, f16b, nullptr, DDIM, 10);
        mfma_gemm7<true, false, true><<<gd, 256, 0, stream>>>(
            f16b, W16d + 1 * (size_t)DDIM * DDIM, bd + 1 * DDIM,
            nullptr, f16a, nullptr, DDIM, 10);
        mfma_gemm7<true, false, true><<<gd, 256, 0, stream>>>(
            f16a, W16d + 2 * (size_t)DDIM * DDIM, bd + 2 * DDIM,
            nullptr, f16b, nullptr, DDIM, 10);

        dim3 go(4, CH / 128);
        mfma_gemm7<false, true, false><<<go, 256, 0, stream>>>(
            f16b, W16o, bo, out + (size_t)e0 * OUTD, nullptr, sperm, OUTD, 4);
    }
}

// Round 29
// 631.806 us; speedup vs baseline: 1.0890x; 1.0378x over previous
//
#include <hip/hip_runtime.h>
#include <math.h>

#define NN   65536
#define EE   32768
#define HH   256
#define KK   24
#define DDIM 1280
#define OUTD 512
#define KT   (DDIM / 32)   // 40 K-steps of 32
#define GCAP 1024
#define RSTRIDE 1296       // 1280 + 16 halves pad

typedef _Float16 half8 __attribute__((ext_vector_type(8)));
typedef _Float16 half4 __attribute__((ext_vector_type(4)));
typedef float    f32x4 __attribute__((ext_vector_type(4)));

__device__ __forceinline__ float elu1(float x) { return x > 0.f ? x : expm1f(x); }

__device__ __forceinline__ void gl16(const void* g, void* l) {
    __builtin_amdgcn_global_load_lds(
        (const __attribute__((address_space(1))) void*)g,
        (__attribute__((address_space(3))) void*)l, 16, 0, 0);
}

// ---------------------------------------------------------------------------
// Fragment-major layout: element (row, k) ->
// idx = ((row>>7)*KT + (k>>5))*4096 + ((row>>4)&7)*512
//       + ((row&15) + 16*((k&31)>>3))*8 + (k&7)   [halves]
// ---------------------------------------------------------------------------
__global__ __launch_bounds__(256) void prep_kernel(
    const float* __restrict__ Wd, const float* __restrict__ Wo,
    const float* __restrict__ X,
    _Float16* __restrict__ W16d, _Float16* __restrict__ W16o,
    _Float16* __restrict__ X16, int* __restrict__ cnt,
    int* __restrict__ sperm)
{
    const int b = blockIdx.x;
    const int lane = threadIdx.x & 63;
    if (b < 2400) {                      // 3 square layers: 800 blocks each
        const int l = b / 800;
        const int s = (b % 800) * 4 + (threadIdx.x >> 6);
        const int nt = s & 7, nb = (s >> 3) % 10, kt = s / 80;
        const int kbase = kt * 32 + 8 * (lane >> 4);
        const int n     = nb * 128 + nt * 16 + (lane & 15);
        const float* W = Wd + (size_t)l * DDIM * DDIM;
        half8 v;
        #pragma unroll
        for (int j = 0; j < 8; ++j) v[j] = (_Float16)W[(size_t)(kbase + j) * DDIM + n];
        ((half8*)(W16d + (size_t)l * DDIM * DDIM))[(size_t)s * 64 + lane] = v;
    } else if (b < 2720) {               // output layer: 320 blocks
        const int s = (b - 2400) * 4 + (threadIdx.x >> 6);
        const int nt = s & 7, nb = (s >> 3) % 4, kt = s / 32;
        const int kbase = kt * 32 + 8 * (lane >> 4);
        const int n     = nb * 128 + nt * 16 + (lane & 15);
        half8 v;
        #pragma unroll
        for (int j = 0; j < 8; ++j) v[j] = (_Float16)Wo[(size_t)(kbase + j) * OUTD + n];
        ((half8*)W16o)[(size_t)s * 64 + lane] = v;
    } else if (b == 2720) {
        if (threadIdx.x < 64) cnt[threadIdx.x] = 0;
    } else if (b < 6817) {               // X conversion: 4096 blocks, 16 rows each
        const int a = b - 2721;
        const int r  = a * 16 + (threadIdx.x >> 4);
        const int c0 = (threadIdx.x & 15) * 16;
        const float4* s4 = (const float4*)(X + (size_t)r * HH + c0);
        const float4 f0 = s4[0], f1 = s4[1], f2 = s4[2], f3 = s4[3];
        half8 o0, o1;
        o0[0]=(_Float16)f0.x; o0[1]=(_Float16)f0.y; o0[2]=(_Float16)f0.z; o0[3]=(_Float16)f0.w;
        o0[4]=(_Float16)f1.x; o0[5]=(_Float16)f1.y; o0[6]=(_Float16)f1.z; o0[7]=(_Float16)f1.w;
        o1[0]=(_Float16)f2.x; o1[1]=(_Float16)f2.y; o1[2]=(_Float16)f2.z; o1[3]=(_Float16)f2.w;
        o1[4]=(_Float16)f3.x; o1[5]=(_Float16)f3.y; o1[6]=(_Float16)f3.z; o1[7]=(_Float16)f3.w;
        *(half8*)(X16 + (size_t)r * HH + c0)     = o0;
        *(half8*)(X16 + (size_t)r * HH + c0 + 8) = o1;
    } else {                             // sperm identity: 32 blocks x 1024 ints
        const int i0 = (b - 6817) * 1024 + threadIdx.x * 4;
        if (i0 < EE)
            *(int4*)(sperm + i0) = make_int4(i0, i0 + 1, i0 + 2, i0 + 3);
    }
}

// bucket edges by graph, LDS-aggregated (order-independent output)
__global__ __launch_bounds__(256) void scatter_kernel(
    const int* __restrict__ src_idx, const int* __restrict__ batch_vec,
    int* __restrict__ perm, int* __restrict__ cnt, int nE)
{
    __shared__ int lc[64];
    __shared__ int lbase[64];
    const int tid = threadIdx.x;
    if (tid < 64) lc[tid] = 0;
    __syncthreads();
    const int e = blockIdx.x * 256 + tid;
    int g = -1, li = 0;
    if (e < nE) {
        g = batch_vec[src_idx[e]];
        li = atomicAdd(&lc[g], 1);
    }
    __syncthreads();
    if (tid < 64 && lc[tid] > 0) lbase[tid] = atomicAdd(&cnt[tid], lc[tid]);
    __syncthreads();
    if (e >= nE) return;
    const int idx = lbase[g] + li;
    if (idx < GCAP) perm[g * GCAP + idx] = e;
}

// compact GCAP-strided perm into dense slot order (sperm[slot] = edge),
// with the 64-entry exclusive prefix computed inline per block (cheap).
__global__ __launch_bounds__(256) void compact_kernel(
    const int* __restrict__ perm, const int* __restrict__ cnt,
    int* __restrict__ sperm)
{
    __shared__ int pre[64];
    if (threadIdx.x == 0) {
        int acc = 0;
        #pragma unroll
        for (int g = 0; g < 64; ++g) { pre[g] = acc; acc += min(cnt[g], GCAP); }
    }
    __syncthreads();
    const int id = blockIdx.x * 256 + threadIdx.x;   // 64*GCAP ids
    const int g = id >> 10, idx = id & (GCAP - 1);
    if (idx < min(cnt[g], GCAP))
        sperm[pre[g] + idx] = perm[id];
}

// ---------------------------------------------------------------------------
// Feature assembly (R24-validated): block = 16 consecutive slots; bucketed
// reads + coalesced fragment-major writes via LDS transpose.
// ---------------------------------------------------------------------------
__global__ __launch_bounds__(256) void feats16t_kernel(
    const _Float16* __restrict__ X16, const int* __restrict__ sperm,
    const int* __restrict__ src_idx, const int* __restrict__ dst_idx,
    const int* __restrict__ batch_vec, const int* __restrict__ ptrv,
    const int* __restrict__ sl, const int* __restrict__ sr,
    const float* __restrict__ elem, const float* __restrict__ emb,
    const float* __restrict__ stat,
    _Float16* __restrict__ F16)
{
    __shared__ _Float16 rows[16][RSTRIDE];

    const int p  = blockIdx.x;
    int lb = p;
    if ((gridDim.x & 7) == 0) {
        const int chunkb = gridDim.x >> 3;
        lb = (p & 7) * chunkb + (p >> 3);
    }
    const int wv   = threadIdx.x >> 6;
    const int lane = threadIdx.x & 63;
    const int s0   = lb * 16;

    const half4* Xh = (const half4*)X16;

    #pragma unroll
    for (int it = 0; it < 4; ++it) {
        const int r = wv * 4 + it;
        const int e = sperm[s0 + r];
        const int src = src_idx[e];
        const int dst = dst_idx[e];
        const int off = ptrv[batch_vec[src]];
        _Float16* row = &rows[r][0];

        *(half4*)(row + 0 * 256 + lane * 4) = Xh[(size_t)src * 64 + lane];
        *(half4*)(row + 1 * 256 + lane * 4) = Xh[(size_t)dst * 64 + lane];

        float4 sL = make_float4(0.f, 0.f, 0.f, 0.f);
        float4 sR = make_float4(0.f, 0.f, 0.f, 0.f);
        int cL = 0, cR = 0;
        #pragma unroll
        for (int k = 0; k < KK; ++k) {
            const int il  = sl[e * KK + k] + off;
            const int ir  = sr[e * KK + k] + off;
            const int okL = il >= 0;
            const int okR = ir >= 0;
            const float wL = okL ? 1.f : 0.f;
            const float wR = okR ? 1.f : 0.f;
            const half4 vl = Xh[(size_t)(okL ? il : 0) * 64 + lane];
            const half4 vr = Xh[(size_t)(okR ? ir : 0) * 64 + lane];
            sL.x += (float)vl[0] * wL; sL.y += (float)vl[1] * wL;
            sL.z += (float)vl[2] * wL; sL.w += (float)vl[3] * wL;
            sR.x += (float)vr[0] * wR; sR.y += (float)vr[1] * wR;
            sR.z += (float)vr[2] * wR; sR.w += (float)vr[3] * wR;
            cL += okL; cR += okR;
        }
        const float rL = cL > 0 ? 1.f / (float)cL : 0.f;
        const float rR = cR > 0 ? 1.f / (float)cR : 0.f;
        half4 h2, h3;
        h2[0]=(_Float16)(sL.x*rL); h2[1]=(_Float16)(sL.y*rL);
        h2[2]=(_Float16)(sL.z*rL); h2[3]=(_Float16)(sL.w*rL);
        h3[0]=(_Float16)(sR.x*rR); h3[1]=(_Float16)(sR.y*rR);
        h3[2]=(_Float16)(sR.z*rR); h3[3]=(_Float16)(sR.w*rR);
        *(half4*)(row + 2 * 256 + lane * 4) = h2;
        *(half4*)(row + 3 * 256 + lane * 4) = h3;

        float4 tail;
        if (lane < 6)       tail = ((const float4*)(elem + (size_t)e * 24))[lane];
        else if (lane < 56) tail = ((const float4*)(emb  + (size_t)e * 200))[lane - 6];
        else                tail = ((const float4*)(stat + (size_t)e * 32))[lane - 56];
        half4 h4;
        h4[0]=(_Float16)tail.x; h4[1]=(_Float16)tail.y;
        h4[2]=(_Float16)tail.z; h4[3]=(_Float16)tail.w;
        *(half4*)(row + 4 * 256 + lane * 4) = h4;
    }

    __syncthreads();

    const int t = threadIdx.x;
    const size_t mt  = (size_t)(s0 >> 7) * KT;
    const int    sr8 = (s0 >> 4) & 7;
    #pragma unroll
    for (int i = 0; i < 10; ++i) {
        const int gc = i * 256 + t;
        const int kt = gc >> 6;
        const int c  = gc & 63;
        const uint4 v = *(const uint4*)&rows[c & 15][kt * 32 + (c >> 4) * 8];
        *(uint4*)(F16 + ((mt + kt) * 4096 + (size_t)sr8 * 512 + (size_t)c * 8)) = v;
    }
}

// ---------------------------------------------------------------------------
// MFMA GEMM (gemm11): depth-2 counted-vmcnt pipeline. Identical schedule
// discipline to the validated gemm7 (vmcnt -> barrier -> reads -> lgkm ->
// barrier -> STAGE -> MFMA) but with 2 LDS buffers (32 KB): LDS occupancy
// cap rises 3 -> 5 blocks/CU (VGPR caps at 4); prefetch slack drops from
// 2 iterations to 1 (~600-900 cyc, vs ~900 HBM / ~500 L3 latency).
// Residual captured from LDS A-tiles; H16 staged through LDS; OUT32
// un-permutes rows via operm.
// ---------------------------------------------------------------------------
template<bool RESID, bool OUT32, bool H16>
__global__ __launch_bounds__(256) void mfma_gemm11(
    const _Float16* __restrict__ A16,
    const _Float16* __restrict__ W16, const float* __restrict__ bias,
    float* __restrict__ C32, _Float16* __restrict__ C16,
    const int* __restrict__ operm,
    int N, int nbN)
{
    __shared__ __align__(16) char sA[2][8192];
    __shared__ __align__(16) char sB[2][8192];

    const int t    = threadIdx.x;
    const int wid  = t >> 6;
    const int lane = t & 63;

    int m_t, n_t;
    if ((gridDim.y & 7) == 0) {
        const int flat = blockIdx.y * gridDim.x + blockIdx.x;
        m_t = (flat & 7) + 8 * (flat / (8 * gridDim.x));
        n_t = (flat >> 3) % gridDim.x;
    } else {
        m_t = blockIdx.y; n_t = blockIdx.x;
    }

    f32x4 acc[2][8];
    #pragma unroll
    for (int i = 0; i < 2; ++i)
        #pragma unroll
        for (int j = 0; j < 8; ++j) acc[i][j] = (f32x4){0.f, 0.f, 0.f, 0.f};

    _Float16 resv[4][2][2][4];

    const char* Abase = (const char*)A16 + (size_t)m_t * KT * 8192;
    const char* Bbase = (const char*)W16;

#define STAGE(d, ktv)                                                           \
    {                                                                           \
        const char* Ak = Abase + (size_t)(ktv) * 8192 + wid * 1024 + lane * 16; \
        const char* Bk = Bbase + ((size_t)(ktv) * nbN + n_t) * 8192             \
                         + wid * 1024 + lane * 16;                              \
        gl16(Ak,        sA[d] + wid * 1024);                                    \
        gl16(Ak + 4096, sA[d] + (4 + wid) * 1024);                              \
        gl16(Bk,        sB[d] + wid * 1024);                                    \
        gl16(Bk + 4096, sB[d] + (4 + wid) * 1024);                              \
    }

    STAGE(0, 0);
    STAGE(1, 1);

    int cur = 0;
    for (int kt = 0; kt < KT; ++kt) {
        // need stage kt; leave stage kt+1 (if any) in flight
        if (kt + 1 < KT) asm volatile("s_waitcnt vmcnt(4)" ::: "memory");
        else             asm volatile("s_waitcnt vmcnt(0)" ::: "memory");
        __builtin_amdgcn_sched_barrier(0);
        __builtin_amdgcn_s_barrier();          // stage kt visible to all waves
        __builtin_amdgcn_sched_barrier(0);

        const half8* pa = (const half8*)sA[cur];
        const half8* pb = (const half8*)sB[cur];
        const half8 af0 = pa[(2 * wid)     * 64 + lane];
        const half8 af1 = pa[(2 * wid + 1) * 64 + lane];
        half8 bf[8];
        #pragma unroll
        for (int j = 0; j < 8; ++j) bf[j] = pb[j * 64 + lane];

        if (RESID) {
            #pragma unroll
            for (int q = 0; q < 4; ++q) {
                if (kt == n_t * 4 + q) {
                    #pragma unroll
                    for (int i = 0; i < 2; ++i)
                        #pragma unroll
                        for (int jj = 0; jj < 2; ++jj)
                            #pragma unroll
                            for (int r = 0; r < 4; ++r) {
                                const int chunk = ((lane >> 4) * 4 + r)
                                                + 16 * (jj * 2 + ((lane >> 3) & 1));
                                resv[q][i][jj][r] = *(const _Float16*)
                                    (sA[cur] + (wid * 2 + i) * 1024
                                             + chunk * 16 + (lane & 7) * 2);
                            }
                }
            }
        }

        asm volatile("s_waitcnt lgkmcnt(0)" ::: "memory");
        __builtin_amdgcn_sched_barrier(0);
        __builtin_amdgcn_s_barrier();          // all waves done reading buf[cur]
        __builtin_amdgcn_sched_barrier(0);

        if (kt + 2 < KT) STAGE(cur, kt + 2);   // overwrite buf[cur] with kt+2
        __builtin_amdgcn_sched_barrier(0);

        __builtin_amdgcn_s_setprio(1);
        #pragma unroll
        for (int j = 0; j < 8; ++j) {
            acc[0][j] = __builtin_amdgcn_mfma_f32_16x16x32_f16(af0, bf[j], acc[0][j], 0, 0, 0);
            acc[1][j] = __builtin_amdgcn_mfma_f32_16x16x32_f16(af1, bf[j], acc[1][j], 0, 0, 0);
        }
        __builtin_amdgcn_s_setprio(0);

        cur ^= 1;
    }
#undef STAGE

    if (H16) {
        char* Cb = (char*)C16 + ((size_t)m_t * 40 + n_t * 4) * 8192;
        #pragma unroll
        for (int q = 0; q < 4; ++q) {
            #pragma unroll
            for (int i = 0; i < 2; ++i)
                #pragma unroll
                for (int jj = 0; jj < 2; ++jj) {
                    const int j = 2 * q + jj;
                    const int col = n_t * 128 + j * 16 + (lane & 15);
                    const float bv = bias[col];
                    #pragma unroll
                    for (int r = 0; r < 4; ++r) {
                        float v = acc[i][j][r] + bv;
                        v = elu1(v) + (float)resv[q][i][jj][r];
                        const int chunk = ((lane >> 4) * 4 + r)
                                        + 16 * (jj * 2 + ((lane >> 3) & 1));
                        *(_Float16*)(sA[0] + (wid * 2 + i) * 1024
                                           + chunk * 16 + (lane & 7) * 2)
                            = (_Float16)v;
                    }
                }
            __syncthreads();
            *(uint4*)(Cb + (size_t)q * 8192 + t * 32) =
                *(const uint4*)(sA[0] + t * 32);
            *(uint4*)(Cb + (size_t)q * 8192 + t * 32 + 16) =
                *(const uint4*)(sA[0] + t * 32 + 16);
            if (q < 3) __syncthreads();
        }
    } else {
        const int m0 = m_t * 128;
        #pragma unroll
        for (int i = 0; i < 2; ++i) {
            #pragma unroll
            for (int j = 0; j < 8; ++j) {
                const int col = n_t * 128 + j * 16 + (lane & 15);
                const float bv = bias[col];
                #pragma unroll
                for (int r = 0; r < 4; ++r) {
                    const int row = m0 + wid * 32 + i * 16 + (lane >> 4) * 4 + r;
                    float v = acc[i][j][r] + bv;
                    if (OUT32) {
                        const int erow = operm[row];   // slot -> edge
                        C32[(size_t)erow * N + col] = v;
                    }
                }
            }
        }
    }
}

extern "C" void kernel_launch(void* const* d_in, const int* in_sizes, int n_in,
                              void* d_out, int out_size, void* d_ws, size_t ws_size,
                              hipStream_t stream) {
    const float* X          = (const float*)d_in[0];
    const int*   edge_index = (const int*)d_in[1];
    const int*   batch_vec  = (const int*)d_in[2];
    const int*   ptrv       = (const int*)d_in[3];
    const int*   sl         = (const int*)d_in[4];
    const int*   sr         = (const int*)d_in[5];
    const float* elem       = (const float*)d_in[6];
    const float* emb        = (const float*)d_in[7];
    const float* stat       = (const float*)d_in[8];
    const float* Wd         = (const float*)d_in[9];
    const float* bd         = (const float*)d_in[10];
    const float* Wo         = (const float*)d_in[11];
    const float* bo         = (const float*)d_in[12];
    float* out = (float*)d_out;

    // ws: [W16d x3 | W16o | X16 | perm | cnt | sperm | h16 a,b]
    _Float16* W16d = (_Float16*)d_ws;
    _Float16* W16o = W16d + (size_t)3 * DDIM * DDIM;
    _Float16* X16  = W16o + (size_t)DDIM * OUTD;
    int* perm    = (int*)(X16 + (size_t)NN * HH);
    int* cnt     = perm + (size_t)64 * GCAP;
    int* sperm   = cnt + 64;
    char* hbase  = (char*)(sperm + EE);
    hbase = (char*)(((size_t)hbase + 255) & ~(size_t)255);
    const size_t rem = ws_size - (size_t)(hbase - (char*)d_ws);

    // Single chunk: working set ~211 MB -> L3-resident; minimal dispatches.
    int CH = EE;
    while (CH > 2048 && (size_t)CH * DDIM * 4 > rem) CH >>= 1;   // 4 B/elem
    _Float16* f16a = (_Float16*)hbase;
    _Float16* f16b = f16a + (size_t)CH * DDIM;

    prep_kernel<<<6849, 256, 0, stream>>>(Wd, Wo, X, W16d, W16o, X16, cnt, sperm);

    for (int e0 = 0; e0 < EE; e0 += CH) {
        scatter_kernel<<<CH / 256, 256, 0, stream>>>(
            edge_index + e0, batch_vec, perm, cnt, CH);
        compact_kernel<<<64 * GCAP / 256, 256, 0, stream>>>(perm, cnt, sperm);

        feats16t_kernel<<<CH / 16, 256, 0, stream>>>(
            X16, sperm, edge_index + e0, edge_index + EE + e0,
            batch_vec, ptrv,
            sl + (size_t)e0 * KK, sr + (size_t)e0 * KK,
            elem + (size_t)e0 * 24, emb + (size_t)e0 * 200,
            stat + (size_t)e0 * 32, f16a);

        dim3 gd(10, CH / 128);
        mfma_gemm11<true, false, true><<<gd, 256, 0, stream>>>(
            f16a, W16d + 0 * (size_t)DDIM * DDIM, bd + 0 * DDIM,
            nullptr, f16b, nullptr, DDIM, 10);
        mfma_gemm11<true, false, true><<<gd, 256, 0, stream>>>(
            f16b, W16d + 1 * (size_t)DDIM * DDIM, bd + 1 * DDIM,
            nullptr, f16a, nullptr, DDIM, 10);
        mfma_gemm11<true, false, true><<<gd, 256, 0, stream>>>(
            f16a, W16d + 2 * (size_t)DDIM * DDIM, bd + 2 * DDIM,
            nullptr, f16b, nullptr, DDIM, 10);

        dim3 go(4, CH / 128);
        mfma_gemm11<false, true, false><<<go, 256, 0, stream>>>(
            f16b, W16o, bo, out + (size_t)e0 * OUTD, nullptr, sperm, OUTD, 4);
    }
}